// Round 14
// baseline (269.726 us; speedup 1.0000x reference)
//
#include <hip/hip_runtime.h>
#include <math.h>

#define N_NODES 512
#define T 128
#define E_EDGES 4096
#define EPS 1e-5f
#define NG 8

typedef unsigned short ushort_t;
typedef short bf16x8 __attribute__((ext_vector_type(8)));
typedef float f32x4 __attribute__((ext_vector_type(4)));

__device__ __forceinline__ ushort_t f2bf(float f) {
    union { float f; unsigned int u; } v; v.f = f;
    unsigned int r = v.u + 0x7fffu + ((v.u >> 16) & 1u);
    return (ushort_t)(r >> 16);
}
__device__ __forceinline__ float bf2f(ushort_t h) {
    union { unsigned int u; float f; } v; v.u = ((unsigned int)h) << 16;
    return v.f;
}
// async global->LDS, 16B per lane, dest = ldsbase + lane*16
__device__ __forceinline__ void gload16(const ushort_t* g, ushort_t* l) {
    __builtin_amdgcn_global_load_lds(
        (const __attribute__((address_space(1))) void*)g,
        (__attribute__((address_space(3))) void*)l, 16, 0, 0);
}

// ---------------- setup: zeroing + all weight convert/transpose ----------------
__global__ void k_setup(const float* __restrict__ Wg1, const float* __restrict__ Wg2,
                        const float* __restrict__ W2,
                        ushort_t* __restrict__ Wg1T, ushort_t* __restrict__ Wg2T,
                        ushort_t* __restrict__ WT2,
                        float* S, float* AH) {
    int gtid = blockIdx.x * 256 + threadIdx.x;
    int stride = gridDim.x * 256;
    for (int i = gtid; i < 229376; i += stride) { int n = i / 1792, k = i % 1792; WT2[i] = f2bf(W2[k * 128 + n]); }
    for (int i = gtid; i < 65536; i += stride)  { int n = i >> 8, k = i & 255;    Wg2T[i] = f2bf(Wg2[k * 256 + n]); }
    for (int i = gtid; i < 16384; i += stride)  { int n = i >> 6, k = i & 63;     Wg1T[i] = f2bf(Wg1[k * 256 + n]); }
    for (int i = gtid; i < 32768; i += stride) AH[i] = 0.f;
    for (int i = gtid; i < 640; i += stride) S[i] = 0.f;
}

// ---------------- graph build: degree + normalized adjacency + bf16 convert, 1 block ----------------
__global__ void k_graph(const int* __restrict__ src, const int* __restrict__ dst,
                        float* AH, ushort_t* __restrict__ AHb) {
    __shared__ int deg[512];
    int tid = threadIdx.x; // 1024
    if (tid < 512) deg[tid] = 0;
    __syncthreads();
    for (int e = tid; e < E_EDGES; e += 1024) atomicAdd(&deg[dst[e]], 1);
    __syncthreads();
    for (int e = tid; e < E_EDGES; e += 1024) {
        int d = dst[e], s = src[e];
        float norm = rsqrtf((float)deg[d] + 1.f) * rsqrtf((float)deg[s] + 1.f);
        atomicAdd(&AH[(d >> 6) * 4096 + (d & 63) * 64 + (s & 63)], norm);
    }
    __syncthreads(); // drains vmcnt: all AH atomics complete & visible
    for (int i = tid; i < 32768; i += 1024) {
        int g = i >> 12, r = (i >> 6) & 63, c = i & 63;
        float v = AH[i];
        if (r == c) v += 1.f / ((float)deg[g * 64 + r] + 1.f);
        AHb[i] = f2bf(v);
    }
}

// ---------------- conv1 (1->64, k=7, SAME) + BN stats + PE MLP, bf16 out ----------------
__global__ void k_conv1(const float* __restrict__ x, const float* __restrict__ W1,
                        const float* __restrict__ pos, const float* __restrict__ Wp1,
                        const float* __restrict__ bp1, const float* __restrict__ Wp2,
                        const float* __restrict__ bp2,
                        ushort_t* __restrict__ Cb, float* S, float* __restrict__ PE) {
    int n = blockIdx.x;
    int tid = threadIdx.x; // 256
    int c = tid & 63, tg = tid >> 6;
    __shared__ float xs[134];
    __shared__ float ws[448];
    __shared__ float red[256];
    __shared__ float hid[64];
    for (int i = tid; i < 448; i += 256) ws[i] = W1[i];
    for (int i = tid; i < 134; i += 256) {
        int t = i - 3;
        xs[i] = (t >= 0 && t < T) ? x[n * T + t] : 0.f;
    }
    __syncthreads();
    float s1 = 0.f, s2 = 0.f;
    for (int t = tg; t < T; t += 4) {
        float acc = 0.f;
        #pragma unroll
        for (int k = 0; k < 7; ++k) acc += xs[t + k] * ws[k * 64 + c];
        Cb[(n * T + t) * 64 + c] = f2bf(acc);
        s1 += acc; s2 += acc * acc;
    }
    red[tid] = s1; __syncthreads();
    if (tg == 0) { float v = red[c] + red[64 + c] + red[128 + c] + red[192 + c]; atomicAdd(&S[c], v); }
    __syncthreads();
    red[tid] = s2; __syncthreads();
    if (tg == 0) { float v = red[c] + red[64 + c] + red[128 + c] + red[192 + c]; atomicAdd(&S[64 + c], v); }
    // PE MLP for this node (threads 0..63)
    if (tid < 64) {
        float p0 = pos[n * 3], p1 = pos[n * 3 + 1], p2 = pos[n * 3 + 2];
        float h = p0 * Wp1[tid] + p1 * Wp1[64 + tid] + p2 * Wp1[128 + tid] + bp1[tid];
        hid[tid] = fmaxf(h, 0.f);
    }
    __syncthreads();
    if (tid < 64) {
        float acc = bp2[tid];
        #pragma unroll
        for (int j = 0; j < 64; ++j) acc += hid[j] * Wp2[j * 64 + tid];
        PE[n * 64 + tid] = acc;
    }
}

// ---------------- fused 2-layer GCN per (graph, t): W in registers, 4 barriers, 2 blocks/CU ----------------
__global__ __launch_bounds__(512) void k_gcn12(const ushort_t* __restrict__ Cb,
                                               const float* __restrict__ S,
                                               const float* __restrict__ g1, const float* __restrict__ b1,
                                               const float* __restrict__ PE,
                                               const ushort_t* __restrict__ W1T,
                                               const ushort_t* __restrict__ W2T,
                                               const ushort_t* __restrict__ AHb,
                                               const float* __restrict__ bg1, const float* __restrict__ bg2,
                                               ushort_t* __restrict__ Gout) {
    __shared__ ushort_t A_lds[64 * 68];    //  8,704 B
    __shared__ ushort_t U1[64 * 264];      // 33,792 B : Xs (stride 72) then D1 row-major (stride 264)
    __shared__ ushort_t U2[256 * 68];      // 34,816 B : P1t then P2t      => 77,312 B total
    int g = blockIdx.x >> 7, t = blockIdx.x & 127;
    int tid = threadIdx.x;
    int l = tid & 63, w = tid >> 6;
    int lrow = l & 15, lko = (l >> 4) * 8, lq = l >> 4;

    // stage A
    {
        int row = tid >> 3, off = (tid & 7) * 8;
        *reinterpret_cast<bf16x8*>(&A_lds[row * 68 + off]) =
            *reinterpret_cast<const bf16x8*>(&AHb[g * 4096 + row * 64 + off]);
    }
    // stage Xs with BN1 affine + ReLU + PE
    {
        int node = tid >> 3, ch0 = (tid & 7) * 8;
        bf16x8 cv = *reinterpret_cast<const bf16x8*>(&Cb[((size_t)(g * 64 + node) * T + t) * 64 + ch0]);
        const float inv = 1.f / (float)(N_NODES * T);
        bf16x8 xv;
        #pragma unroll
        for (int j = 0; j < 8; ++j) {
            int c = ch0 + j;
            float mean = S[c] * inv;
            float var  = S[64 + c] * inv - mean * mean;
            float sc = g1[c] * rsqrtf(var + EPS);
            float sh = b1[c] - mean * sc;
            float v = fmaxf(bf2f((ushort_t)cv[j]) * sc + sh, 0.f) + PE[(g * 64 + node) * 64 + c];
            xv[j] = (short)f2bf(v);
        }
        *reinterpret_cast<bf16x8*>(&U1[node * 72 + ch0]) = xv;
    }
    // W1 fragments (registers, direct from L2)
    bf16x8 w1f[2][2];
    #pragma unroll
    for (int kc = 0; kc < 2; ++kc)
        #pragma unroll
        for (int ni = 0; ni < 2; ++ni)
            w1f[kc][ni] = *reinterpret_cast<const bf16x8*>(
                &W1T[(size_t)(w * 32 + ni * 16 + lrow) * 64 + kc * 32 + lko]);
    __syncthreads(); // B1: Xs + A visible

    // ---- phase 1: P1 = X @ W1^T (K=64) ----
    f32x4 p[4][2];
    #pragma unroll
    for (int i = 0; i < 4; ++i)
        #pragma unroll
        for (int j = 0; j < 2; ++j) p[i][j] = (f32x4){0.f, 0.f, 0.f, 0.f};
    #pragma unroll
    for (int kc = 0; kc < 2; ++kc) {
        bf16x8 a[4];
        #pragma unroll
        for (int mi = 0; mi < 4; ++mi)
            a[mi] = *reinterpret_cast<const bf16x8*>(&U1[(mi * 16 + lrow) * 72 + kc * 32 + lko]);
        #pragma unroll
        for (int mi = 0; mi < 4; ++mi)
            #pragma unroll
            for (int ni = 0; ni < 2; ++ni)
                p[mi][ni] = __builtin_amdgcn_mfma_f32_16x16x32_bf16(a[mi], w1f[kc][ni], p[mi][ni], 0, 0, 0);
    }
    // W2 fragments (issue early; 64 VGPR, static indexing)
    bf16x8 w2f[8][2];
    #pragma unroll
    for (int kc = 0; kc < 8; ++kc)
        #pragma unroll
        for (int ni = 0; ni < 2; ++ni)
            w2f[kc][ni] = *reinterpret_cast<const bf16x8*>(
                &W2T[(size_t)(w * 32 + ni * 16 + lrow) * 256 + kc * 32 + lko]);
    // write P1t [col][node]
    #pragma unroll
    for (int mi = 0; mi < 4; ++mi) {
        int node0 = mi * 16 + lq * 4;
        #pragma unroll
        for (int ni = 0; ni < 2; ++ni) {
            int col = w * 32 + ni * 16 + lrow;
            unsigned u0 = (unsigned)f2bf(p[mi][ni][0]) | ((unsigned)f2bf(p[mi][ni][1]) << 16);
            unsigned u1 = (unsigned)f2bf(p[mi][ni][2]) | ((unsigned)f2bf(p[mi][ni][3]) << 16);
            *reinterpret_cast<unsigned*>(&U2[col * 68 + node0]) = u0;
            *reinterpret_cast<unsigned*>(&U2[col * 68 + node0 + 2]) = u1;
        }
    }
    __syncthreads(); // B2: P1t visible; all Xs reads done

    // ---- phase 2: D1 = A @ P1t + bg1, ReLU -> D1 row-major in U1 ----
    f32x4 d[4][2];
    #pragma unroll
    for (int i = 0; i < 4; ++i)
        #pragma unroll
        for (int j = 0; j < 2; ++j) d[i][j] = (f32x4){0.f, 0.f, 0.f, 0.f};
    #pragma unroll
    for (int kc = 0; kc < 2; ++kc) {
        bf16x8 a2[4], b2[2];
        #pragma unroll
        for (int mi = 0; mi < 4; ++mi)
            a2[mi] = *reinterpret_cast<const bf16x8*>(&A_lds[(mi * 16 + lrow) * 68 + kc * 32 + lko]);
        #pragma unroll
        for (int ni = 0; ni < 2; ++ni)
            b2[ni] = *reinterpret_cast<const bf16x8*>(&U2[(w * 32 + ni * 16 + lrow) * 68 + kc * 32 + lko]);
        #pragma unroll
        for (int mi = 0; mi < 4; ++mi)
            #pragma unroll
            for (int ni = 0; ni < 2; ++ni)
                d[mi][ni] = __builtin_amdgcn_mfma_f32_16x16x32_bf16(a2[mi], b2[ni], d[mi][ni], 0, 0, 0);
    }
    #pragma unroll
    for (int ni = 0; ni < 2; ++ni) {
        int col = w * 32 + ni * 16 + lrow;
        float bs = bg1[col];
        #pragma unroll
        for (int mi = 0; mi < 4; ++mi) {
            #pragma unroll
            for (int r = 0; r < 4; ++r) {
                int node = mi * 16 + lq * 4 + r;
                U1[node * 264 + col] = f2bf(fmaxf(d[mi][ni][r] + bs, 0.f));
            }
        }
    }
    __syncthreads(); // B3: D1rm visible; P1t reads done

    // ---- phase 3: P2 = D1 @ W2^T (K=256), W2 from registers, no barriers ----
    f32x4 q[4][2];
    #pragma unroll
    for (int i = 0; i < 4; ++i)
        #pragma unroll
        for (int j = 0; j < 2; ++j) q[i][j] = (f32x4){0.f, 0.f, 0.f, 0.f};
    #pragma unroll
    for (int kc = 0; kc < 8; ++kc) {
        bf16x8 a[4];
        #pragma unroll
        for (int mi = 0; mi < 4; ++mi)
            a[mi] = *reinterpret_cast<const bf16x8*>(&U1[(mi * 16 + lrow) * 264 + kc * 32 + lko]);
        #pragma unroll
        for (int mi = 0; mi < 4; ++mi)
            #pragma unroll
            for (int ni = 0; ni < 2; ++ni)
                q[mi][ni] = __builtin_amdgcn_mfma_f32_16x16x32_bf16(a[mi], w2f[kc][ni], q[mi][ni], 0, 0, 0);
    }
    // write P2t into U2
    #pragma unroll
    for (int mi = 0; mi < 4; ++mi) {
        int node0 = mi * 16 + lq * 4;
        #pragma unroll
        for (int ni = 0; ni < 2; ++ni) {
            int col = w * 32 + ni * 16 + lrow;
            unsigned u0 = (unsigned)f2bf(q[mi][ni][0]) | ((unsigned)f2bf(q[mi][ni][1]) << 16);
            unsigned u1 = (unsigned)f2bf(q[mi][ni][2]) | ((unsigned)f2bf(q[mi][ni][3]) << 16);
            *reinterpret_cast<unsigned*>(&U2[col * 68 + node0]) = u0;
            *reinterpret_cast<unsigned*>(&U2[col * 68 + node0 + 2]) = u1;
        }
    }
    __syncthreads(); // B4: P2t visible; D1 reads done

    // ---- phase 4: D2 = A @ P2t + bg2, ReLU -> global ----
    f32x4 d2[4][2];
    #pragma unroll
    for (int i = 0; i < 4; ++i)
        #pragma unroll
        for (int j = 0; j < 2; ++j) d2[i][j] = (f32x4){0.f, 0.f, 0.f, 0.f};
    #pragma unroll
    for (int kc = 0; kc < 2; ++kc) {
        bf16x8 a2[4], b2[2];
        #pragma unroll
        for (int mi = 0; mi < 4; ++mi)
            a2[mi] = *reinterpret_cast<const bf16x8*>(&A_lds[(mi * 16 + lrow) * 68 + kc * 32 + lko]);
        #pragma unroll
        for (int ni = 0; ni < 2; ++ni)
            b2[ni] = *reinterpret_cast<const bf16x8*>(&U2[(w * 32 + ni * 16 + lrow) * 68 + kc * 32 + lko]);
        #pragma unroll
        for (int mi = 0; mi < 4; ++mi)
            #pragma unroll
            for (int ni = 0; ni < 2; ++ni)
                d2[mi][ni] = __builtin_amdgcn_mfma_f32_16x16x32_bf16(a2[mi], b2[ni], d2[mi][ni], 0, 0, 0);
    }
    #pragma unroll
    for (int ni = 0; ni < 2; ++ni) {
        int col = w * 32 + ni * 16 + lrow;
        float bs = bg2[col];
        #pragma unroll
        for (int mi = 0; mi < 4; ++mi) {
            #pragma unroll
            for (int r = 0; r < 4; ++r) {
                int node = mi * 16 + lq * 4 + r;
                Gout[((size_t)(g * 64 + node) * T + t) * 256 + col] =
                    f2bf(fmaxf(d2[mi][ni][r] + bs, 0.f));
            }
        }
    }
}

// ---------------- conv2: quarter-Hs + 3-deep counted-vmcnt W pipeline, fused stats + pooled sums ----------------
__global__ __launch_bounds__(512) void k_conv2_mfma(const ushort_t* __restrict__ H,
                                                    const ushort_t* __restrict__ WT2,
                                                    float* __restrict__ P1S, float* S) {
    __shared__ ushort_t Hs[128 * 72];    // 18,432 B : one cin quarter (64 ch)
    __shared__ ushort_t Ws[3][128 * 64]; // 49,152 B : unpadded, XOR-swizzled content, 3-deep
    __shared__ float sS1[128];
    __shared__ float sS2[128];
    int n = blockIdx.x;
    int tid = threadIdx.x;
    int l = tid & 63, wid = tid >> 6;
    int wr = wid >> 1, wc = wid & 1;
    int lrow = l & 15, lko = (l >> 4) * 8, lq = l >> 4;

    if (tid < 128) { sS1[tid] = 0.f; sS2[tid] = 0.f; }

    f32x4 acc[2][4];
    #pragma unroll
    for (int i = 0; i < 2; ++i)
        #pragma unroll
        for (int j = 0; j < 4; ++j) acc[i][j] = (f32x4){0.f, 0.f, 0.f, 0.f};

    int wrow0 = wid * 16 + (l >> 3);
    int wslot = ((l & 7) ^ (l >> 3)) * 8;

    auto stageHs = [&](int q) {
        #pragma unroll
        for (int it = 0; it < 2; ++it) {
            int lin = it * 512 + tid;
            int row = lin >> 3, off = (lin & 7) * 8;
            *reinterpret_cast<bf16x8*>(&Hs[row * 72 + off]) =
                *reinterpret_cast<const bf16x8*>(&H[((size_t)n * T + row) * 256 + q * 64 + off]);
        }
    };
    auto issueW = [&](int c) {
        int q = c / 7, tap = c % 7;
        int koff = tap * 256 + q * 64;
        int buf = c % 3;
        #pragma unroll
        for (int i = 0; i < 2; ++i)
            gload16(&WT2[(size_t)(wrow0 + i * 8) * 1792 + koff + wslot],
                    &Ws[buf][wid * 1024 + i * 512]);
    };

    stageHs(0);
    issueW(0);
    issueW(1);
    __syncthreads();

    for (int c = 0; c < 28; ++c) {
        if (c > 0) {
            if (c % 7 == 0) {
                __builtin_amdgcn_s_barrier();
                __builtin_amdgcn_sched_barrier(0);
                stageHs(c / 7);
            }
            if (c < 27) asm volatile("s_waitcnt vmcnt(2) lgkmcnt(0)" ::: "memory");
            else        asm volatile("s_waitcnt vmcnt(0) lgkmcnt(0)" ::: "memory");
            __builtin_amdgcn_sched_barrier(0);
            __builtin_amdgcn_s_barrier();
            __builtin_amdgcn_sched_barrier(0);
        }
        if (c + 2 < 28) issueW(c + 2);
        int tap = c % 7;
        int cur = c % 3;
        bf16x8 a[2][2], b[4][2];
        #pragma unroll
        for (int mi = 0; mi < 2; ++mi) {
            int row = wr * 32 + mi * 16 + lrow + tap;
            if (row > 127) row = 127;
            #pragma unroll
            for (int ks = 0; ks < 2; ++ks)
                a[mi][ks] = *reinterpret_cast<const bf16x8*>(&Hs[row * 72 + ks * 32 + lko]);
        }
        #pragma unroll
        for (int ni = 0; ni < 4; ++ni) {
            int row = wc * 64 + ni * 16 + lrow;
            #pragma unroll
            for (int ks = 0; ks < 2; ++ks) {
                int slot = (ks * 4 + lq) ^ (lrow & 7);
                b[ni][ks] = *reinterpret_cast<const bf16x8*>(&Ws[cur][row * 64 + slot * 8]);
            }
        }
        #pragma unroll
        for (int ks = 0; ks < 2; ++ks)
            #pragma unroll
            for (int mi = 0; mi < 2; ++mi)
                #pragma unroll
                for (int ni = 0; ni < 4; ++ni)
                    acc[mi][ni] = __builtin_amdgcn_mfma_f32_16x16x32_bf16(a[mi][ks], b[ni][ks], acc[mi][ni], 0, 0, 0);
    }
    #pragma unroll
    for (int ni = 0; ni < 4; ++ni) {
        int col = wc * 64 + ni * 16 + lrow;
        float s1 = 0.f, s2 = 0.f;
        #pragma unroll
        for (int mi = 0; mi < 2; ++mi) {
            int t0 = wr * 32 + mi * 16 + lq * 4;
            float psum = 0.f;
            #pragma unroll
            for (int r = 0; r < 4; ++r) {
                float v = acc[mi][ni][r];
                if (t0 + r < 122) { s1 += v; s2 += v * v; }
                psum += v;
            }
            if (t0 <= 116) P1S[((size_t)n * 30 + (t0 >> 2)) * 128 + col] = psum;
        }
        atomicAdd(&sS1[col], s1);
        atomicAdd(&sS2[col], s2);
    }
    __syncthreads();
    if (tid < 128) {
        atomicAdd(&S[128 + tid], sS1[tid]);
        atomicAdd(&S[256 + tid], sS2[tid]);
    }
}

// ---------------- BN2 affine + ReLU + graph-mean, no atomics ----------------
__global__ void k_gpool(const float* __restrict__ P1S, const float* __restrict__ S,
                        const float* __restrict__ g2, const float* __restrict__ b2,
                        float* __restrict__ GP) {
    int g = blockIdx.x / 30, tp = blockIdx.x % 30;
    int c = threadIdx.x; // 128
    const float inv = 1.f / (float)(N_NODES * 122);
    float mean = S[128 + c] * inv;
    float var  = S[256 + c] * inv - mean * mean;
    float sc = g2[c] * rsqrtf(var + EPS);
    float sh = b2[c] - mean * sc;
    float s = 0.f;
    for (int i = 0; i < 64; ++i) {
        float psum = P1S[((size_t)(g * 64 + i) * 30 + tp) * 128 + c];
        s += fmaxf(psum * 0.25f * sc + sh, 0.f);
    }
    GP[((size_t)g * 30 + tp) * 128 + c] = s * (1.f / 64.f);
}

// ---------------- conv3 (128->128, k=3, VALID) + BN3 stats ----------------
__global__ void k_conv3(const float* __restrict__ GP, const float* __restrict__ W3,
                        float* __restrict__ C3, float* S) {
    int b = blockIdx.x / 28, t = blockIdx.x % 28;
    int c = threadIdx.x; // 128
    __shared__ float gs[3 * 128];
    for (int i = c; i < 384; i += 128) gs[i] = GP[((size_t)b * 30 + t) * 128 + i];
    __syncthreads();
    float acc = 0.f;
    for (int i = 0; i < 384; ++i) acc += gs[i] * W3[i * 128 + c];
    C3[((size_t)b * 28 + t) * 128 + c] = acc;
    atomicAdd(&S[384 + c], acc);
    atomicAdd(&S[512 + c], acc * acc);
}

// ---------------- BN3 apply + avgpool4 + ReLU ----------------
__global__ void k_bn3pool(const float* __restrict__ C3, const float* __restrict__ S,
                          const float* __restrict__ g3, const float* __restrict__ b3,
                          float* __restrict__ P2) {
    int b = blockIdx.x;  // 8
    int c = threadIdx.x; // 128
    const float inv = 1.f / (float)(NG * 28);
    float mean = S[384 + c] * inv;
    float var  = S[512 + c] * inv - mean * mean;
    float sc = g3[c] * rsqrtf(var + EPS);
    float sh = b3[c] - mean * sc;
    for (int tp = 0; tp < 7; ++tp) {
        float s = 0.f;
        #pragma unroll
        for (int i = 0; i < 4; ++i) s += C3[((size_t)b * 28 + tp * 4 + i) * 128 + c];
        P2[((size_t)b * 7 + tp) * 128 + c] = fmaxf(s * 0.25f * sc + sh, 0.f);
    }
}

// ---------------- final linear + log_softmax ----------------
__global__ void k_final(const float* __restrict__ P2, const float* __restrict__ Wd,
                        const float* __restrict__ bd, float* __restrict__ out) {
    int tid = threadIdx.x; // 32
    int b = tid >> 2, j = tid & 3;
    float acc = bd[j];
    for (int i = 0; i < 896; ++i) acc += P2[b * 896 + i] * Wd[i * 4 + j];
    float m = acc;
    m = fmaxf(m, __shfl_xor(m, 1, 4));
    m = fmaxf(m, __shfl_xor(m, 2, 4));
    float e = expf(acc - m);
    float s = e;
    s += __shfl_xor(s, 1, 4);
    s += __shfl_xor(s, 2, 4);
    out[tid] = acc - m - logf(s);
}

extern "C" void kernel_launch(void* const* d_in, const int* in_sizes, int n_in,
                              void* d_out, int out_size, void* d_ws, size_t ws_size,
                              hipStream_t stream) {
    const float* x   = (const float*)d_in[0];
    const float* pos = (const float*)d_in[1];
    const int*   ei  = (const int*)d_in[2];
    const float* W1  = (const float*)d_in[4];
    const float* g1  = (const float*)d_in[5];
    const float* b1  = (const float*)d_in[6];
    const float* Wp1 = (const float*)d_in[7];
    const float* bp1 = (const float*)d_in[8];
    const float* Wp2 = (const float*)d_in[9];
    const float* bp2 = (const float*)d_in[10];
    const float* Wg1 = (const float*)d_in[11];
    const float* bg1 = (const float*)d_in[12];
    const float* Wg2 = (const float*)d_in[13];
    const float* bg2 = (const float*)d_in[14];
    const float* W2  = (const float*)d_in[15];
    const float* g2  = (const float*)d_in[16];
    const float* b2  = (const float*)d_in[17];
    const float* W3  = (const float*)d_in[18];
    const float* g3  = (const float*)d_in[19];
    const float* b3  = (const float*)d_in[20];
    const float* Wd  = (const float*)d_in[21];
    const float* bd  = (const float*)d_in[22];
    float* out = (float*)d_out;

    float* ws = (float*)d_ws;
    float* P1S  = ws;                  //  1,966,080 f : conv2 pooled sums
    float* PE   = P1S + 1966080;       //     32,768 f
    float* GPb  = PE + 32768;          //     30,720 f
    float* C3   = GPb + 30720;         //     28,672 f
    float* P2   = C3 + 28672;          //      7,168 f
    float* S    = P2 + 7168;           //        640 f
    float* AH   = S + 640;             //     32,768 f
    ushort_t* Cb   = (ushort_t*)(AH + 32768); //  4,194,304 us : conv1 out bf16
    ushort_t* Gout = Cb + 4194304;            // 16,777,216 us : GCN stack out
    ushort_t* Wg1T = Gout + 16777216;         //     16,384 us
    ushort_t* Wg2T = Wg1T + 16384;            //     65,536 us
    ushort_t* WT2  = Wg2T + 65536;            //    229,376 us
    ushort_t* AHb  = WT2 + 229376;            //     32,768 us
    const int* srcv = ei;
    const int* dstv = ei + E_EDGES;

    hipLaunchKernelGGL(k_setup,  dim3(896), dim3(256),  0, stream, Wg1, Wg2, W2, Wg1T, Wg2T, WT2, S, AH);
    hipLaunchKernelGGL(k_graph,  dim3(1),   dim3(1024), 0, stream, srcv, dstv, AH, AHb);
    hipLaunchKernelGGL(k_conv1,  dim3(512), dim3(256),  0, stream, x, W1, pos, Wp1, bp1, Wp2, bp2, Cb, S, PE);
    hipLaunchKernelGGL(k_gcn12,  dim3(1024), dim3(512), 0, stream, Cb, S, g1, b1, PE, Wg1T, Wg2T, AHb, bg1, bg2, Gout);
    hipLaunchKernelGGL(k_conv2_mfma, dim3(512), dim3(512), 0, stream, Gout, WT2, P1S, S);
    hipLaunchKernelGGL(k_gpool,  dim3(240), dim3(128),  0, stream, P1S, S, g2, b2, GPb);
    hipLaunchKernelGGL(k_conv3,  dim3(224), dim3(128),  0, stream, GPb, W3, C3, S);
    hipLaunchKernelGGL(k_bn3pool, dim3(8),  dim3(128),  0, stream, C3, S, g3, b3, P2);
    hipLaunchKernelGGL(k_final,  dim3(1),   dim3(32),   0, stream, P2, Wd, bd, out);
}